// Round 11
// baseline (160.767 us; speedup 1.0000x reference)
//
#include <hip/hip_runtime.h>
#include <hip/hip_bf16.h>

// GRU cell v11: two-kernel split so each kernel's register demand fits the
// 128-reg budget of 4 waves/SIMD with ZERO spills.
//  k1 gru_zr: [B,512]x[512,512] GEMM (B=[Wz|Wr] panels, A=[x|h] in LDS).
//     epilogue: d_out dword(row,col) = {lo16: z bf16, hi16: r*h_prev bf16}.
//  k2 gru_h : [B,512]x[512,256] GEMM (A=[x|rh], rh staged from d_out hi16).
//     epilogue: h = z*h_prev + (1-z)*tanh(acc+bh), overwrites d_out.
// Both: wave tile 32x64 (fa=2, fb=4, acc 32), C_w=64 (halved A-LDS traffic),
// B via distance-1 sched_barrier-fenced reg double-buffer, XOR-granule LDS.

typedef __attribute__((ext_vector_type(8))) short s8v;           // 8 bf16 = 4 VGPR
typedef __attribute__((ext_vector_type(8))) unsigned short us8;
typedef __attribute__((ext_vector_type(4))) float f32x4;
typedef __attribute__((ext_vector_type(4))) float f4v;
typedef __attribute__((ext_vector_type(4))) unsigned int u4v;

__device__ __forceinline__ float bf2f(unsigned short u) {
  union { unsigned int i; float f; } c; c.i = ((unsigned int)u) << 16; return c.f;
}
__device__ __forceinline__ unsigned short f2bf(float f) {
  union { float f; unsigned int i; } c; c.f = f;
  return (unsigned short)((c.i + 0x7fffu + ((c.i >> 16) & 1u)) >> 16);  // RNE
}
__device__ __forceinline__ float sig_(float s)  { return 1.0f / (1.0f + __expf(-s)); }
__device__ __forceinline__ float tanh_(float s) { return 2.0f / (1.0f + __expf(-2.0f * s)) - 1.0f; }

// ---------------- weight prep: fp32 [K][N] -> bf16 fragment-major tiles ----------------
// Tile (nt, kt) = 16 n x 32 k = 512 shorts (1 KB), lane-major:
//   n = nt*16 + (lane&15), k = kt*32 + (lane>>4)*8 + e ; tile index t = nt*16 + kt.
// wzr: nt 0..15 = Wz/Uz, nt 16..31 = Wr/Ur (k<256 -> W, else U). whh: nt 0..15 = Wh/Uh.
__global__ void gru_prep(const float* __restrict__ Wz, const float* __restrict__ Uz,
                         const float* __restrict__ Wr, const float* __restrict__ Ur,
                         const float* __restrict__ Wh, const float* __restrict__ Uh,
                         unsigned short* __restrict__ wzr, unsigned short* __restrict__ whh) {
  int idx = blockIdx.x * 256 + threadIdx.x;
  if (idx < 512 * 512) {
    int t = idx >> 9, lane = (idx >> 3) & 63, e = idx & 7;
    int nt = t >> 4, kt = t & 15;
    int n = nt * 16 + (lane & 15);
    int k = kt * 32 + ((lane >> 4) << 3) + e;
    int nn = n & 255;
    float v;
    if (n < 256) v = (k < 256) ? Wz[k * 256 + nn] : Uz[(k - 256) * 256 + nn];
    else         v = (k < 256) ? Wr[k * 256 + nn] : Ur[(k - 256) * 256 + nn];
    wzr[idx] = f2bf(v);
  } else if (idx < 512 * 512 + 256 * 512) {
    int j = idx - 512 * 512;
    int t = j >> 9, lane = (j >> 3) & 63, e = j & 7;
    int nt = t >> 4, kt = t & 15;
    int n = nt * 16 + (lane & 15);
    int k = kt * 32 + ((lane >> 4) << 3) + e;
    float v = (k < 256) ? Wh[k * 256 + n] : Uh[(k - 256) * 256 + n];
    whh[j] = f2bf(v);
  }
}

#define MFMA(a, b, c) __builtin_amdgcn_mfma_f32_16x16x32_bf16((a), (b), (c), 0, 0, 0)

// ---- K=256 half-sweep, fb=4: distance-1 fenced B double-buffer, A from LDS ----
// Bt = panel base + lane*8 ; fb tile stride 8192 ; kt stride 512.
// A rows = arow0 + {0,16} + l15 (fa=2); A is XOR-granule swizzled.
__device__ __forceinline__ void sweep8w(f32x4 acc[2][4],
    const unsigned short* __restrict__ Bt,
    const unsigned short* A, int arow0, int l15, int lg4)
{
  const int r7 = l15 & 7;
  const unsigned short* Ab = A + (arow0 + l15) * 256;
  s8v bb[2][4];
#pragma unroll
  for (int fb = 0; fb < 4; ++fb) bb[0][fb] = *(const s8v*)(Bt + fb * 8192);
#pragma unroll
  for (int g = 0; g < 8; ++g) {
    if (g < 7) {
#pragma unroll
      for (int fb = 0; fb < 4; ++fb)
        bb[(g + 1) & 1][fb] = *(const s8v*)(Bt + (g + 1) * 512 + fb * 8192);
    }
    __builtin_amdgcn_sched_barrier(0);
    const unsigned short* ap = Ab + ((g * 4 + lg4) ^ r7) * 8;
    s8v af0 = *(const s8v*)(ap);
    s8v af1 = *(const s8v*)(ap + 16 * 256);
#pragma unroll
    for (int fb = 0; fb < 4; ++fb) {
      acc[0][fb] = MFMA(af0, bb[g & 1][fb], acc[0][fb]);
      acc[1][fb] = MFMA(af1, bb[g & 1][fb], acc[1][fb]);
    }
    __builtin_amdgcn_sched_barrier(0);
  }
}

__device__ __forceinline__ float ldsA_get(const unsigned short* A, int row, int col) {
  int gp = ((col >> 3) ^ (row & 7));
  return bf2f(A[row * 256 + gp * 8 + (col & 7)]);
}

// ================= k1: z & r*h -> packed gate dwords in d_out =================
// 1024 blocks x 1024 thr. R=64 rows. 16 waves = 2 wr x 8 wc. N=512 (z|r).
__global__ __launch_bounds__(1024, 4) void gru_zr(
    const float* __restrict__ x, const float* __restrict__ hp,
    const unsigned short* __restrict__ wzr,
    const float* __restrict__ bz, const float* __restrict__ br,
    unsigned short* __restrict__ outg)
{
  __shared__ __align__(16) unsigned short x_l[64 * 256];   // 32 KB
  __shared__ __align__(16) unsigned short h_l[64 * 256];   // 32 KB

  const int tid = threadIdx.x;
  const int lane = tid & 63;
  const int wv = tid >> 6;                   // 0..15
  const int wr = wv >> 3;                    // 0..1 : 32-row slice
  const int wc = wv & 7;                     // 0..7 : 64-col slice of N=512
  const int l15 = lane & 15, lg4 = lane >> 4;
  const int row0 = blockIdx.x * 64;

  // ---- stage x, h (fp32 -> bf16), granule-XOR layout; 2 granules per array
  {
    const int srow = tid >> 4;               // 0..63
    const int part = tid & 15;
    const float* xs = x  + (size_t)(row0 + srow) * 256 + part * 16;
    const float* hs = hp + (size_t)(row0 + srow) * 256 + part * 16;
    unsigned short* xd = x_l + srow * 256;
    unsigned short* hd = h_l + srow * 256;
    const int r7 = srow & 7;
#pragma unroll
    for (int j = 0; j < 2; ++j) {
      int gp = (part * 2 + j) ^ r7;
      f4v v0 = *(const f4v*)(xs + j * 8);
      f4v v1 = *(const f4v*)(xs + j * 8 + 4);
      us8 o;
      o[0]=f2bf(v0[0]); o[1]=f2bf(v0[1]); o[2]=f2bf(v0[2]); o[3]=f2bf(v0[3]);
      o[4]=f2bf(v1[0]); o[5]=f2bf(v1[1]); o[6]=f2bf(v1[2]); o[7]=f2bf(v1[3]);
      *(us8*)(xd + gp * 8) = o;
    }
#pragma unroll
    for (int j = 0; j < 2; ++j) {
      int gp = (part * 2 + j) ^ r7;
      f4v v0 = *(const f4v*)(hs + j * 8);
      f4v v1 = *(const f4v*)(hs + j * 8 + 4);
      us8 o;
      o[0]=f2bf(v0[0]); o[1]=f2bf(v0[1]); o[2]=f2bf(v0[2]); o[3]=f2bf(v0[3]);
      o[4]=f2bf(v1[0]); o[5]=f2bf(v1[1]); o[6]=f2bf(v1[2]); o[7]=f2bf(v1[3]);
      *(us8*)(hd + gp * 8) = o;
    }
  }
  __syncthreads();

  f32x4 acc[2][4];
#pragma unroll
  for (int fa = 0; fa < 2; ++fa)
#pragma unroll
    for (int fb = 0; fb < 4; ++fb) acc[fa][fb] = (f32x4){0.f,0.f,0.f,0.f};

  const unsigned short* Bt = wzr + wc * 32768 + lane * 8;   // nt = wc*4 + fb
  sweep8w(acc, Bt,        x_l, wr * 32, l15, lg4);          // W half (k 0..255)
  sweep8w(acc, Bt + 4096, h_l, wr * 32, l15, lg4);          // U half (k 256..511)

  // ---- epilogue: z -> lo16, r*h_prev -> hi16 of out dword (wave-uniform branch)
  const bool isz = (wc < 4);
#pragma unroll
  for (int fb = 0; fb < 4; ++fb) {
    const int nloc = wc * 64 + fb * 16 + l15;          // 0..511
    const int col = isz ? nloc : nloc - 256;           // gate-local col
    const float bv = isz ? bz[col] : br[col];
#pragma unroll
    for (int fa = 0; fa < 2; ++fa) {
      f32x4 a = acc[fa][fb];
#pragma unroll
      for (int i = 0; i < 4; ++i) {
        const int row = wr * 32 + fa * 16 + lg4 * 4 + i;
        const float s = sig_(a[i] + bv);
        const size_t oi = ((size_t)(row0 + row) * 256 + col) * 2;
        if (isz) outg[oi]     = f2bf(s);
        else     outg[oi + 1] = f2bf(s * ldsA_get(h_l, row, col));
      }
    }
  }
}

// ================= k2: h_hat GEMM + final blend, overwrites d_out =================
// 1024 blocks x 512 thr. R=64 rows. 8 waves = 2 wr x 4 wc. N=256.
__global__ __launch_bounds__(512, 4) void gru_h(
    const float* __restrict__ x, const float* __restrict__ hp,
    const unsigned short* __restrict__ whh,
    const float* __restrict__ bh,
    float* __restrict__ out)
{
  __shared__ __align__(16) unsigned short x_l[64 * 256];    // 32 KB
  __shared__ __align__(16) unsigned short rh_l[64 * 256];   // 32 KB

  const int tid = threadIdx.x;
  const int lane = tid & 63;
  const int wv = tid >> 6;                   // 0..7
  const int wr = wv >> 2;                    // 0..1
  const int wc = wv & 3;                     // 0..3 : 64-col slice of N=256
  const int l15 = lane & 15, lg4 = lane >> 4;
  const int row0 = blockIdx.x * 64;

  const unsigned int*   outw  = (const unsigned int*)out;
  const unsigned short* out16 = (const unsigned short*)out;

  // ---- stage x (fp32->bf16) and rh (hi16 of gate dwords), granule-XOR layout
  {
    const int srow = tid >> 3;               // 0..63
    const int part = tid & 7;                // 4 granules per array
    const float* xs = x + (size_t)(row0 + srow) * 256 + part * 32;
    const unsigned int* gs = outw + (size_t)(row0 + srow) * 256 + part * 32;
    unsigned short* xd = x_l + srow * 256;
    unsigned short* rd = rh_l + srow * 256;
    const int r7 = srow & 7;
#pragma unroll
    for (int j = 0; j < 4; ++j) {
      int gp = (part * 4 + j) ^ r7;
      f4v v0 = *(const f4v*)(xs + j * 8);
      f4v v1 = *(const f4v*)(xs + j * 8 + 4);
      us8 o;
      o[0]=f2bf(v0[0]); o[1]=f2bf(v0[1]); o[2]=f2bf(v0[2]); o[3]=f2bf(v0[3]);
      o[4]=f2bf(v1[0]); o[5]=f2bf(v1[1]); o[6]=f2bf(v1[2]); o[7]=f2bf(v1[3]);
      *(us8*)(xd + gp * 8) = o;
    }
#pragma unroll
    for (int j = 0; j < 4; ++j) {
      int gp = (part * 4 + j) ^ r7;
      u4v d0 = *(const u4v*)(gs + j * 8);
      u4v d1 = *(const u4v*)(gs + j * 8 + 4);
      us8 o;
      o[0]=(unsigned short)(d0[0]>>16); o[1]=(unsigned short)(d0[1]>>16);
      o[2]=(unsigned short)(d0[2]>>16); o[3]=(unsigned short)(d0[3]>>16);
      o[4]=(unsigned short)(d1[0]>>16); o[5]=(unsigned short)(d1[1]>>16);
      o[6]=(unsigned short)(d1[2]>>16); o[7]=(unsigned short)(d1[3]>>16);
      *(us8*)(rd + gp * 8) = o;
    }
  }
  __syncthreads();

  f32x4 acc[2][4];
#pragma unroll
  for (int fa = 0; fa < 2; ++fa)
#pragma unroll
    for (int fb = 0; fb < 4; ++fb) acc[fa][fb] = (f32x4){0.f,0.f,0.f,0.f};

  const unsigned short* Bt = whh + wc * 32768 + lane * 8;   // nt = wc*4 + fb
  sweep8w(acc, Bt,        x_l,  wr * 32, l15, lg4);         // Wh half
  sweep8w(acc, Bt + 4096, rh_l, wr * 32, l15, lg4);         // Uh half (rh)

  // ---- epilogue: h = z*h_prev + (1-z)*tanh(acc + bh); z = lo16 (data-dep ordered)
#pragma unroll
  for (int fb = 0; fb < 4; ++fb) {
    const int col = wc * 64 + fb * 16 + l15;
    const float bv = bh[col];
#pragma unroll
    for (int fa = 0; fa < 2; ++fa) {
      f32x4 a = acc[fa][fb];
#pragma unroll
      for (int i = 0; i < 4; ++i) {
        const int row = wr * 32 + fa * 16 + lg4 * 4 + i;
        const size_t oi = (size_t)(row0 + row) * 256 + col;
        const float z = bf2f(out16[oi * 2]);     // lo16, feeds the store -> ordered
        const float hpv = hp[oi];
        const float hh = tanh_(a[i] + bv);
        out[oi] = z * hpv + (1.0f - z) * hh;
      }
    }
  }
}

extern "C" void kernel_launch(void* const* d_in, const int* in_sizes, int n_in,
                              void* d_out, int out_size, void* d_ws, size_t ws_size,
                              hipStream_t stream) {
  const float* x  = (const float*)d_in[0];
  const float* hp = (const float*)d_in[1];
  const float* Wz = (const float*)d_in[2];
  const float* Uz = (const float*)d_in[3];
  const float* bz = (const float*)d_in[4];
  const float* Wr = (const float*)d_in[5];
  const float* Ur = (const float*)d_in[6];
  const float* br = (const float*)d_in[7];
  const float* Wh = (const float*)d_in[8];
  const float* Uh = (const float*)d_in[9];
  const float* bh = (const float*)d_in[10];

  if (ws_size < (size_t)(512 * 512 + 256 * 512) * sizeof(unsigned short)) return;  // need 768 KB

  unsigned short* wzr = (unsigned short*)d_ws;
  unsigned short* whh = wzr + 512 * 512;

  gru_prep<<<1536, 256, 0, stream>>>(Wz, Uz, Wr, Ur, Wh, Uh, wzr, whh);
  gru_zr<<<1024, 1024, 0, stream>>>(x, hp, wzr, bz, br, (unsigned short*)d_out);
  gru_h<<<1024, 512, 0, stream>>>(x, hp, whh, bh, (float*)d_out);
}

// Round 12
// 153.267 us; speedup vs baseline: 1.0489x; 1.0489x over previous
//
#include <hip/hip_runtime.h>
#include <hip/hip_bf16.h>

// GRU cell v12: two split GEMM kernels, zero persistent gate registers,
// z/r column-paired IN-WAVE (packed dword gate stores, coalesced),
// continuous 16-group K-loop with depth-2 (triple-buffer) B prefetch.
// Each kernel: 512 thr, 64-row tile, 64 KB LDS, launch_bounds(512,4) -> 2 blocks/CU.
//  gru_zr (grid 2048 = 1024 row-tiles x 2 col-flavors):
//    d_out dword(row,col) = { lo16: z bf16, hi16: (r*h_prev) bf16 }
//  gru_h  (grid 1024): A=[x|rh] GEMM + blend, overwrites d_out with h (f32).

typedef __attribute__((ext_vector_type(8))) short s8v;           // 8 bf16 = 4 VGPR
typedef __attribute__((ext_vector_type(8))) unsigned short us8;
typedef __attribute__((ext_vector_type(4))) float f32x4;
typedef __attribute__((ext_vector_type(4))) float f4v;
typedef __attribute__((ext_vector_type(4))) unsigned int u4v;

__device__ __forceinline__ float bf2f(unsigned short u) {
  union { unsigned int i; float f; } c; c.i = ((unsigned int)u) << 16; return c.f;
}
__device__ __forceinline__ unsigned short f2bf(float f) {
  union { float f; unsigned int i; } c; c.f = f;
  return (unsigned short)((c.i + 0x7fffu + ((c.i >> 16) & 1u)) >> 16);  // RNE
}
__device__ __forceinline__ unsigned int pkdw(float lo, float hi) {
  return (unsigned int)f2bf(lo) | ((unsigned int)f2bf(hi) << 16);
}
__device__ __forceinline__ float sig_(float s)  { return 1.0f / (1.0f + __expf(-s)); }
__device__ __forceinline__ float tanh_(float s) { return 2.0f / (1.0f + __expf(-2.0f * s)) - 1.0f; }

// ---------------- weight prep: fp32 [K][N] -> bf16 fragment-major tiles ----------------
// Tile (nt, kt) = 16 n x 32 k = 512 shorts (1 KB), lane-major:
//   n = nt*16 + (lane&15), k = kt*32 + (lane>>4)*8 + e ; tile index t = nt*16 + kt.
// wzr: nt 0..15 = Wz/Uz, nt 16..31 = Wr/Ur (k<256 -> W, else U). whh: nt 0..15 = Wh/Uh.
__global__ void gru_prep(const float* __restrict__ Wz, const float* __restrict__ Uz,
                         const float* __restrict__ Wr, const float* __restrict__ Ur,
                         const float* __restrict__ Wh, const float* __restrict__ Uh,
                         unsigned short* __restrict__ wzr, unsigned short* __restrict__ whh) {
  int idx = blockIdx.x * 256 + threadIdx.x;
  if (idx < 512 * 512) {
    int t = idx >> 9, lane = (idx >> 3) & 63, e = idx & 7;
    int nt = t >> 4, kt = t & 15;
    int n = nt * 16 + (lane & 15);
    int k = kt * 32 + ((lane >> 4) << 3) + e;
    int nn = n & 255;
    float v;
    if (n < 256) v = (k < 256) ? Wz[k * 256 + nn] : Uz[(k - 256) * 256 + nn];
    else         v = (k < 256) ? Wr[k * 256 + nn] : Ur[(k - 256) * 256 + nn];
    wzr[idx] = f2bf(v);
  } else if (idx < 512 * 512 + 256 * 512) {
    int j = idx - 512 * 512;
    int t = j >> 9, lane = (j >> 3) & 63, e = j & 7;
    int nt = t >> 4, kt = t & 15;
    int n = nt * 16 + (lane & 15);
    int k = kt * 32 + ((lane >> 4) << 3) + e;
    float v = (k < 256) ? Wh[k * 256 + n] : Uh[(k - 256) * 256 + n];
    whh[j] = f2bf(v);
  }
}

#define MFMA(a, b, c) __builtin_amdgcn_mfma_f32_16x16x32_bf16((a), (b), (c), 0, 0, 0)

// ---- continuous K=512 loop (16 groups), depth-2 B prefetch (3-slot buffer) ----
// b0p..b3p: lane-adjusted bases of the 4 B fragment-column streams (kt stride 512).
// A: groups 0..7 from Ax, 8..15 from Ah (both XOR-granule-swizzled [64][256]).
__device__ __forceinline__ void sweep16(f32x4 acc[2][4],
    const unsigned short* __restrict__ b0p, const unsigned short* __restrict__ b1p,
    const unsigned short* __restrict__ b2p, const unsigned short* __restrict__ b3p,
    const unsigned short* Ax, const unsigned short* Ah,
    int wr, int l15, int lg4)
{
  const int r7 = l15 & 7;
  const unsigned short* Abx = Ax + (wr * 32 + l15) * 256;
  const unsigned short* Abh = Ah + (wr * 32 + l15) * 256;
  s8v b[3][4];
  b[0][0] = *(const s8v*)(b0p);       b[0][1] = *(const s8v*)(b1p);
  b[0][2] = *(const s8v*)(b2p);       b[0][3] = *(const s8v*)(b3p);
  b[1][0] = *(const s8v*)(b0p + 512); b[1][1] = *(const s8v*)(b1p + 512);
  b[1][2] = *(const s8v*)(b2p + 512); b[1][3] = *(const s8v*)(b3p + 512);
#pragma unroll
  for (int g = 0; g < 16; ++g) {
    if (g + 2 < 16) {
      const int s = (g + 2) % 3;
      b[s][0] = *(const s8v*)(b0p + (g + 2) * 512);
      b[s][1] = *(const s8v*)(b1p + (g + 2) * 512);
      b[s][2] = *(const s8v*)(b2p + (g + 2) * 512);
      b[s][3] = *(const s8v*)(b3p + (g + 2) * 512);
    }
    __builtin_amdgcn_sched_barrier(0);
    const unsigned short* Ab = (g < 8) ? Abx : Abh;
    const int kk = g & 7;
    const unsigned short* ap = Ab + ((kk * 4 + lg4) ^ r7) * 8;
    s8v af0 = *(const s8v*)(ap);
    s8v af1 = *(const s8v*)(ap + 16 * 256);
    const int c = g % 3;
    acc[0][0] = MFMA(af0, b[c][0], acc[0][0]);
    acc[0][1] = MFMA(af0, b[c][1], acc[0][1]);
    acc[0][2] = MFMA(af0, b[c][2], acc[0][2]);
    acc[0][3] = MFMA(af0, b[c][3], acc[0][3]);
    acc[1][0] = MFMA(af1, b[c][0], acc[1][0]);
    acc[1][1] = MFMA(af1, b[c][1], acc[1][1]);
    acc[1][2] = MFMA(af1, b[c][2], acc[1][2]);
    acc[1][3] = MFMA(af1, b[c][3], acc[1][3]);
    __builtin_amdgcn_sched_barrier(0);
  }
}

__device__ __forceinline__ float ldsA_get(const unsigned short* A, int row, int col) {
  int gp = ((col >> 3) ^ (row & 7));
  return bf2f(A[row * 256 + gp * 8 + (col & 7)]);
}

// ================= k1: z & r*h -> packed gate dwords in d_out =================
// grid 2048: blockIdx = rowtile*2 + flavor. 512 thr, 8 waves = 2 wr x 4 wc.
// Wave covers 32 z-cols AND the SAME 32 r-cols (fb 0,1 = z; fb 2,3 = r).
__global__ __launch_bounds__(512, 4) void gru_zr(
    const float* __restrict__ x, const float* __restrict__ hp,
    const unsigned short* __restrict__ wzr,
    const float* __restrict__ bz, const float* __restrict__ br,
    unsigned int* __restrict__ outg)
{
  __shared__ __align__(16) unsigned short x_l[64 * 256];   // 32 KB
  __shared__ __align__(16) unsigned short h_l[64 * 256];   // 32 KB

  const int tid = threadIdx.x;
  const int lane = tid & 63;
  const int wv = tid >> 6;
  const int wr = wv >> 2;                    // 0..1 : 32-row slice
  const int wc = wv & 3;                     // 0..3
  const int by = blockIdx.x & 1;             // col flavor
  const int row0 = (blockIdx.x >> 1) * 64;
  const int l15 = lane & 15, lg4 = lane >> 4;
  const int cb = by * 128 + wc * 32;         // wave's col base (z and r)

  const unsigned short* base = wzr + lane * 8 + (size_t)(cb >> 4) * 8192;
  const unsigned short* b0p = base;                // z cols cb..cb+15
  const unsigned short* b1p = base + 8192;         // z cols cb+16..cb+31
  const unsigned short* b2p = base + 131072;       // r cols cb..cb+15
  const unsigned short* b3p = base + 139264;       // r cols cb+16..cb+31

  // ---- stage x, h tiles to LDS (fp32 -> bf16), granule-XOR layout
  {
    const int srow = tid >> 3;               // 0..63
    const int part = tid & 7;
    const float* xs = x  + (size_t)(row0 + srow) * 256 + part * 32;
    const float* hs = hp + (size_t)(row0 + srow) * 256 + part * 32;
    unsigned short* xd = x_l + srow * 256;
    unsigned short* hd = h_l + srow * 256;
    const int r7 = srow & 7;
#pragma unroll
    for (int j = 0; j < 4; ++j) {
      int gp = (part * 4 + j) ^ r7;
      f4v v0 = *(const f4v*)(xs + j * 8);
      f4v v1 = *(const f4v*)(xs + j * 8 + 4);
      us8 o;
      o[0]=f2bf(v0[0]); o[1]=f2bf(v0[1]); o[2]=f2bf(v0[2]); o[3]=f2bf(v0[3]);
      o[4]=f2bf(v1[0]); o[5]=f2bf(v1[1]); o[6]=f2bf(v1[2]); o[7]=f2bf(v1[3]);
      *(us8*)(xd + gp * 8) = o;
    }
#pragma unroll
    for (int j = 0; j < 4; ++j) {
      int gp = (part * 4 + j) ^ r7;
      f4v v0 = *(const f4v*)(hs + j * 8);
      f4v v1 = *(const f4v*)(hs + j * 8 + 4);
      us8 o;
      o[0]=f2bf(v0[0]); o[1]=f2bf(v0[1]); o[2]=f2bf(v0[2]); o[3]=f2bf(v0[3]);
      o[4]=f2bf(v1[0]); o[5]=f2bf(v1[1]); o[6]=f2bf(v1[2]); o[7]=f2bf(v1[3]);
      *(us8*)(hd + gp * 8) = o;
    }
  }
  __syncthreads();

  f32x4 acc[2][4];
#pragma unroll
  for (int fa = 0; fa < 2; ++fa)
#pragma unroll
    for (int fb = 0; fb < 4; ++fb) acc[fa][fb] = (f32x4){0.f,0.f,0.f,0.f};

  sweep16(acc, b0p, b1p, b2p, b3p, x_l, h_l, wr, l15, lg4);

  // ---- epilogue: dword(row,col) = { z, r*h_prev } ; coalesced dword stores
#pragma unroll
  for (int c16 = 0; c16 < 2; ++c16) {
    const int col = cb + c16 * 16 + l15;
    const float bvz = bz[col], bvr = br[col];
#pragma unroll
    for (int fa = 0; fa < 2; ++fa) {
      f32x4 az = acc[fa][c16];
      f32x4 ar = acc[fa][2 + c16];
#pragma unroll
      for (int i = 0; i < 4; ++i) {
        const int row = wr * 32 + fa * 16 + lg4 * 4 + i;
        const float z = sig_(az[i] + bvz);
        const float r = sig_(ar[i] + bvr);
        const float h = ldsA_get(h_l, row, col);
        outg[(size_t)(row0 + row) * 256 + col] = pkdw(z, r * h);
      }
    }
  }
}

// ================= k2: h_hat GEMM + blend, overwrites d_out =================
// grid 1024. 512 thr, 8 waves = 2 wr x 4 wc (wave 32 rows x 64 cols).
__global__ __launch_bounds__(512, 4) void gru_h(
    const float* __restrict__ x, const float* __restrict__ hp,
    const unsigned short* __restrict__ whh,
    const float* __restrict__ bh,
    float* __restrict__ out)
{
  __shared__ __align__(16) unsigned short x_l[64 * 256];    // 32 KB
  __shared__ __align__(16) unsigned short rh_l[64 * 256];   // 32 KB

  const int tid = threadIdx.x;
  const int lane = tid & 63;
  const int wv = tid >> 6;
  const int wr = wv >> 2;                    // 0..1
  const int wc = wv & 3;                     // 0..3
  const int l15 = lane & 15, lg4 = lane >> 4;
  const int row0 = blockIdx.x * 64;

  const unsigned int* outw = (const unsigned int*)out;

  const unsigned short* base = whh + lane * 8 + (size_t)wc * 32768;
  const unsigned short* b0p = base;
  const unsigned short* b1p = base + 8192;
  const unsigned short* b2p = base + 16384;
  const unsigned short* b3p = base + 24576;

  // ---- stage x (fp32->bf16) and rh (hi16 of gate dwords), granule-XOR layout
  {
    const int srow = tid >> 3;               // 0..63
    const int part = tid & 7;
    const float* xs = x + (size_t)(row0 + srow) * 256 + part * 32;
    const unsigned int* gs = outw + (size_t)(row0 + srow) * 256 + part * 32;
    unsigned short* xd = x_l + srow * 256;
    unsigned short* rd = rh_l + srow * 256;
    const int r7 = srow & 7;
#pragma unroll
    for (int j = 0; j < 4; ++j) {
      int gp = (part * 4 + j) ^ r7;
      f4v v0 = *(const f4v*)(xs + j * 8);
      f4v v1 = *(const f4v*)(xs + j * 8 + 4);
      us8 o;
      o[0]=f2bf(v0[0]); o[1]=f2bf(v0[1]); o[2]=f2bf(v0[2]); o[3]=f2bf(v0[3]);
      o[4]=f2bf(v1[0]); o[5]=f2bf(v1[1]); o[6]=f2bf(v1[2]); o[7]=f2bf(v1[3]);
      *(us8*)(xd + gp * 8) = o;
    }
#pragma unroll
    for (int j = 0; j < 4; ++j) {
      int gp = (part * 4 + j) ^ r7;
      u4v d0 = *(const u4v*)(gs + j * 8);
      u4v d1 = *(const u4v*)(gs + j * 8 + 4);
      us8 o;
      o[0]=(unsigned short)(d0[0]>>16); o[1]=(unsigned short)(d0[1]>>16);
      o[2]=(unsigned short)(d0[2]>>16); o[3]=(unsigned short)(d0[3]>>16);
      o[4]=(unsigned short)(d1[0]>>16); o[5]=(unsigned short)(d1[1]>>16);
      o[6]=(unsigned short)(d1[2]>>16); o[7]=(unsigned short)(d1[3]>>16);
      *(us8*)(rd + gp * 8) = o;
    }
  }
  __syncthreads();

  f32x4 acc[2][4];
#pragma unroll
  for (int fa = 0; fa < 2; ++fa)
#pragma unroll
    for (int fb = 0; fb < 4; ++fb) acc[fa][fb] = (f32x4){0.f,0.f,0.f,0.f};

  sweep16(acc, b0p, b1p, b2p, b3p, x_l, rh_l, wr, l15, lg4);

  // ---- epilogue: h = z*h_prev + (1-z)*tanh(acc+bh); z from lo16 of own dword
#pragma unroll
  for (int fb = 0; fb < 4; ++fb) {
    const int col = wc * 64 + fb * 16 + l15;
    const float bv = bh[col];
#pragma unroll
    for (int fa = 0; fa < 2; ++fa) {
      f32x4 a = acc[fa][fb];
#pragma unroll
      for (int i = 0; i < 4; ++i) {
        const int row = wr * 32 + fa * 16 + lg4 * 4 + i;
        const size_t oi = (size_t)(row0 + row) * 256 + col;
        const float z = bf2f((unsigned short)(outw[oi] & 0xffffu));
        const float hh = tanh_(a[i] + bv);
        out[oi] = z * hp[oi] + (1.0f - z) * hh;
      }
    }
  }
}

extern "C" void kernel_launch(void* const* d_in, const int* in_sizes, int n_in,
                              void* d_out, int out_size, void* d_ws, size_t ws_size,
                              hipStream_t stream) {
  const float* x  = (const float*)d_in[0];
  const float* hp = (const float*)d_in[1];
  const float* Wz = (const float*)d_in[2];
  const float* Uz = (const float*)d_in[3];
  const float* bz = (const float*)d_in[4];
  const float* Wr = (const float*)d_in[5];
  const float* Ur = (const float*)d_in[6];
  const float* br = (const float*)d_in[7];
  const float* Wh = (const float*)d_in[8];
  const float* Uh = (const float*)d_in[9];
  const float* bh = (const float*)d_in[10];

  if (ws_size < (size_t)(512 * 512 + 256 * 512) * sizeof(unsigned short)) return;  // need 768 KB

  unsigned short* wzr = (unsigned short*)d_ws;
  unsigned short* whh = wzr + 512 * 512;

  gru_prep<<<1536, 256, 0, stream>>>(Wz, Uz, Wr, Ur, Wh, Uh, wzr, whh);
  gru_zr<<<2048, 512, 0, stream>>>(x, hp, wzr, bz, br, (unsigned int*)d_out);
  gru_h<<<1024, 512, 0, stream>>>(x, hp, whh, bh, (float*)d_out);
}

// Round 13
// 131.620 us; speedup vs baseline: 1.2214x; 1.1645x over previous
//
#include <hip/hip_runtime.h>
#include <hip/hip_bf16.h>

// GRU cell v13: fused single kernel, v8 geometry (1024 blocks x 512 thr, 64-row
// tile, 8 waves x (64x32), 64 KB LDS, 2 blocks/CU) made register-allocatable:
//  - pass order r -> z -> h; z gate parked in DEAD h_l as thread-private LDS
//    slots (same-thread write/read: no barriers, no VGPR cost)
//  - epilogues read h_prev from GLOBAL fp32 (h_l only feeds MFMA A-frags)
//  - only persistent regs: rhp 16. Total demand ~119 < 128 budget.
//  - continuous 16-group K-sweeps (x->h halves, one drain), distance-2 ring-3
//    B prefetch, sched_barrier fenced, static indices.
//  - __float2bfloat16 (v_cvt_pk_bf16_f32) for all fp32->bf16.

typedef __attribute__((ext_vector_type(8))) short s8v;           // 8 bf16 = 4 VGPR
typedef __attribute__((ext_vector_type(8))) unsigned short us8;
typedef __attribute__((ext_vector_type(4))) float f32x4;
typedef __attribute__((ext_vector_type(4))) float f4v;

__device__ __forceinline__ float bf2f(unsigned short u) {
  union { unsigned int i; float f; } c; c.i = ((unsigned int)u) << 16; return c.f;
}
__device__ __forceinline__ unsigned short f2bf(float f) {
  __hip_bfloat16 b = __float2bfloat16(f);            // RNE, pairs into v_cvt_pk_bf16_f32
  union { __hip_bfloat16 b; unsigned short u; } c; c.b = b; return c.u;
}
__device__ __forceinline__ unsigned int pk2(float lo, float hi) {
  return (unsigned int)f2bf(lo) | ((unsigned int)f2bf(hi) << 16);
}
__device__ __forceinline__ float sig_(float s)  { return 1.0f / (1.0f + __expf(-s)); }
__device__ __forceinline__ float tanh_(float s) { return 2.0f / (1.0f + __expf(-2.0f * s)) - 1.0f; }

// ---------------- weight prep: fp32 [K][N] -> bf16 fragment-major tiles ----------------
// Tile (nt, kt) = 16 n x 32 k = 512 shorts (1 KB), lane-major:
//   n = nt*16 + (lane&15), k = kt*32 + (lane>>4)*8 + e ; tile index t = nt*16 + kt.
// wzr: nt 0..15 = Wz/Uz, nt 16..31 = Wr/Ur (k<256 -> W, else U). whh: nt 0..15 = Wh/Uh.
__global__ void gru_prep(const float* __restrict__ Wz, const float* __restrict__ Uz,
                         const float* __restrict__ Wr, const float* __restrict__ Ur,
                         const float* __restrict__ Wh, const float* __restrict__ Uh,
                         unsigned short* __restrict__ wzr, unsigned short* __restrict__ whh) {
  int idx = blockIdx.x * 256 + threadIdx.x;
  if (idx < 512 * 512) {
    int t = idx >> 9, lane = (idx >> 3) & 63, e = idx & 7;
    int nt = t >> 4, kt = t & 15;
    int n = nt * 16 + (lane & 15);
    int k = kt * 32 + ((lane >> 4) << 3) + e;
    int nn = n & 255;
    float v;
    if (n < 256) v = (k < 256) ? Wz[k * 256 + nn] : Uz[(k - 256) * 256 + nn];
    else         v = (k < 256) ? Wr[k * 256 + nn] : Ur[(k - 256) * 256 + nn];
    wzr[idx] = f2bf(v);
  } else if (idx < 512 * 512 + 256 * 512) {
    int j = idx - 512 * 512;
    int t = j >> 9, lane = (j >> 3) & 63, e = j & 7;
    int nt = t >> 4, kt = t & 15;
    int n = nt * 16 + (lane & 15);
    int k = kt * 32 + ((lane >> 4) << 3) + e;
    float v = (k < 256) ? Wh[k * 256 + n] : Uh[(k - 256) * 256 + n];
    whh[j] = f2bf(v);
  }
}

#define MFMA(a, b, c) __builtin_amdgcn_mfma_f32_16x16x32_bf16((a), (b), (c), 0, 0, 0)

// ---- continuous K=512 sweep (16 groups): A = x half then h half; fa=4, fb=2 ----
// Distance-2 prefetch, ring-3 B buffer, static indices, sched_barrier fenced.
__device__ __forceinline__ void sweep16(f32x4 acc[4][2],
    const unsigned short* __restrict__ b0p, const unsigned short* __restrict__ b1p,
    const unsigned short* Ax, const unsigned short* Ah, int l15, int lg4)
{
  const int r7 = l15 & 7;
  const unsigned short* Abx = Ax + l15 * 256;
  const unsigned short* Abh = Ah + l15 * 256;
  s8v b[3][2];
  b[0][0] = *(const s8v*)(b0p);        b[0][1] = *(const s8v*)(b1p);
  b[1][0] = *(const s8v*)(b0p + 512);  b[1][1] = *(const s8v*)(b1p + 512);
#pragma unroll
  for (int g = 0; g < 16; ++g) {
    if (g + 2 < 16) {
      const int s = (g + 2) % 3;
      b[s][0] = *(const s8v*)(b0p + (g + 2) * 512);
      b[s][1] = *(const s8v*)(b1p + (g + 2) * 512);
    }
    __builtin_amdgcn_sched_barrier(0);
    const unsigned short* Ab = (g < 8) ? Abx : Abh;
    const int kk = g & 7;
    const unsigned short* ap = Ab + (((kk * 4 + lg4) ^ r7) * 8);
    s8v af0 = *(const s8v*)(ap);
    s8v af1 = *(const s8v*)(ap + 16 * 256);
    s8v af2 = *(const s8v*)(ap + 32 * 256);
    s8v af3 = *(const s8v*)(ap + 48 * 256);
    const int c = g % 3;
    acc[0][0] = MFMA(af0, b[c][0], acc[0][0]);  acc[0][1] = MFMA(af0, b[c][1], acc[0][1]);
    acc[1][0] = MFMA(af1, b[c][0], acc[1][0]);  acc[1][1] = MFMA(af1, b[c][1], acc[1][1]);
    acc[2][0] = MFMA(af2, b[c][0], acc[2][0]);  acc[2][1] = MFMA(af2, b[c][1], acc[2][1]);
    acc[3][0] = MFMA(af3, b[c][0], acc[3][0]);  acc[3][1] = MFMA(af3, b[c][1], acc[3][1]);
    __builtin_amdgcn_sched_barrier(0);
  }
}

// ---- 8-group half sweep (for the h pass halves), same pipeline ----
__device__ __forceinline__ void sweep8(f32x4 acc[4][2],
    const unsigned short* __restrict__ b0p, const unsigned short* __restrict__ b1p,
    const unsigned short* A, int l15, int lg4)
{
  const int r7 = l15 & 7;
  const unsigned short* Ab = A + l15 * 256;
  s8v b[3][2];
  b[0][0] = *(const s8v*)(b0p);        b[0][1] = *(const s8v*)(b1p);
  b[1][0] = *(const s8v*)(b0p + 512);  b[1][1] = *(const s8v*)(b1p + 512);
#pragma unroll
  for (int g = 0; g < 8; ++g) {
    if (g + 2 < 8) {
      const int s = (g + 2) % 3;
      b[s][0] = *(const s8v*)(b0p + (g + 2) * 512);
      b[s][1] = *(const s8v*)(b1p + (g + 2) * 512);
    }
    __builtin_amdgcn_sched_barrier(0);
    const unsigned short* ap = Ab + (((g * 4 + lg4) ^ r7) * 8);
    s8v af0 = *(const s8v*)(ap);
    s8v af1 = *(const s8v*)(ap + 16 * 256);
    s8v af2 = *(const s8v*)(ap + 32 * 256);
    s8v af3 = *(const s8v*)(ap + 48 * 256);
    const int c = g % 3;
    acc[0][0] = MFMA(af0, b[c][0], acc[0][0]);  acc[0][1] = MFMA(af0, b[c][1], acc[0][1]);
    acc[1][0] = MFMA(af1, b[c][0], acc[1][0]);  acc[1][1] = MFMA(af1, b[c][1], acc[1][1]);
    acc[2][0] = MFMA(af2, b[c][0], acc[2][0]);  acc[2][1] = MFMA(af2, b[c][1], acc[2][1]);
    acc[3][0] = MFMA(af3, b[c][0], acc[3][0]);  acc[3][1] = MFMA(af3, b[c][1], acc[3][1]);
    __builtin_amdgcn_sched_barrier(0);
  }
}

__device__ __forceinline__ void ldsA_put(unsigned short* A, int row, int col, unsigned short v) {
  int gp = ((col >> 3) ^ (row & 7));
  A[row * 256 + gp * 8 + (col & 7)] = v;
}

// ---------------- main fused kernel: 64 rows per block, 8 waves ----------------
__global__ __launch_bounds__(512, 4) void gru_main(
    const float* __restrict__ x, const float* __restrict__ hp,
    const unsigned short* __restrict__ wzr, const unsigned short* __restrict__ whh,
    const float* __restrict__ bz, const float* __restrict__ br, const float* __restrict__ bh,
    float* __restrict__ out)
{
  __shared__ __align__(16) unsigned short x_l[64 * 256];   // 32 KB; later holds rh
  __shared__ __align__(16) unsigned short h_l[64 * 256];   // 32 KB; later holds z (as dwords)

  const int tid = threadIdx.x;
  const int lane = tid & 63;
  const int wv = tid >> 6;                   // 0..7 : wave's 32-col slice
  const int l15 = lane & 15, lg4 = lane >> 4;
  const int row0 = blockIdx.x * 64;

  const unsigned short* Bz = wzr + wv * 16384 + lane * 8;            // z: nt = wv*2
  const unsigned short* Br = wzr + 131072 + wv * 16384 + lane * 8;   // r: nt = wv*2+16
  const unsigned short* Bh = whh + wv * 16384 + lane * 8;            // h

  // ---- stage x, h tiles to LDS (fp32 -> bf16 via cvt_pk), granule-XOR layout
  {
    const int srow = tid >> 3;               // 0..63
    const int part = tid & 7;                // 4 granules each
    const float* xs = x  + (size_t)(row0 + srow) * 256 + part * 32;
    const float* hs = hp + (size_t)(row0 + srow) * 256 + part * 32;
    unsigned short* xd = x_l + srow * 256;
    unsigned short* hd = h_l + srow * 256;
    const int r7 = srow & 7;
#pragma unroll
    for (int j = 0; j < 4; ++j) {
      int gp = (part * 4 + j) ^ r7;
      f4v v0 = *(const f4v*)(xs + j * 8);
      f4v v1 = *(const f4v*)(xs + j * 8 + 4);
      us8 o;
      o[0]=f2bf(v0[0]); o[1]=f2bf(v0[1]); o[2]=f2bf(v0[2]); o[3]=f2bf(v0[3]);
      o[4]=f2bf(v1[0]); o[5]=f2bf(v1[1]); o[6]=f2bf(v1[2]); o[7]=f2bf(v1[3]);
      *(us8*)(xd + gp * 8) = o;
    }
#pragma unroll
    for (int j = 0; j < 4; ++j) {
      int gp = (part * 4 + j) ^ r7;
      f4v v0 = *(const f4v*)(hs + j * 8);
      f4v v1 = *(const f4v*)(hs + j * 8 + 4);
      us8 o;
      o[0]=f2bf(v0[0]); o[1]=f2bf(v0[1]); o[2]=f2bf(v0[2]); o[3]=f2bf(v0[3]);
      o[4]=f2bf(v1[0]); o[5]=f2bf(v1[1]); o[6]=f2bf(v1[2]); o[7]=f2bf(v1[3]);
      *(us8*)(hd + gp * 8) = o;
    }
  }
  __syncthreads();                           // B1

  f32x4 acc[4][2];
  unsigned int rhp[4][2][2];                 // ONLY persistent gate state: 16 VGPR

  // ===== PASS r: r = sigmoid(x Wr + h Ur + br); rh = r * h_prev(global fp32)
#pragma unroll
  for (int fa = 0; fa < 4; ++fa)
#pragma unroll
    for (int fb = 0; fb < 2; ++fb) acc[fa][fb] = (f32x4){0.f,0.f,0.f,0.f};
  sweep16(acc, Br, Br + 8192, x_l, h_l, l15, lg4);
#pragma unroll
  for (int fb = 0; fb < 2; ++fb) {
    const int col = wv * 32 + fb * 16 + l15;
    const float bv = br[col];
#pragma unroll
    for (int fa = 0; fa < 4; ++fa) {
      f32x4 a = acc[fa][fb];
#pragma unroll
      for (int p = 0; p < 2; ++p) {
        const int row = fa * 16 + lg4 * 4 + 2 * p;
        const float r0 = sig_(a[2*p]   + bv);
        const float r1 = sig_(a[2*p+1] + bv);
        const float h0 = hp[(size_t)(row0 + row)     * 256 + col];
        const float h1 = hp[(size_t)(row0 + row + 1) * 256 + col];
        rhp[fa][fb][p] = pk2(r0 * h0, r1 * h1);
      }
    }
  }

  // ===== PASS z: z = sigmoid(x Wz + h Uz + bz) -> parked in h_l (thread-private)
#pragma unroll
  for (int fa = 0; fa < 4; ++fa)
#pragma unroll
    for (int fb = 0; fb < 2; ++fb) acc[fa][fb] = (f32x4){0.f,0.f,0.f,0.f};
  sweep16(acc, Bz, Bz + 8192, x_l, h_l, l15, lg4);
  __syncthreads();                           // B2: all waves done reading h_l
  {
    unsigned int* zl = (unsigned int*)h_l;   // [32 row-pairs][256 cols] dwords
#pragma unroll
    for (int fb = 0; fb < 2; ++fb) {
      const int col = wv * 32 + fb * 16 + l15;
      const float bv = bz[col];
#pragma unroll
      for (int fa = 0; fa < 4; ++fa) {
        f32x4 a = acc[fa][fb];
#pragma unroll
        for (int p = 0; p < 2; ++p) {
          const int rp = fa * 8 + lg4 * 2 + p;          // row-pair index
          zl[rp * 256 + col] = pk2(sig_(a[2*p] + bv), sig_(a[2*p+1] + bv));
        }
      }
    }
  }
  // no barrier needed: zl slots are read back by the SAME thread only

  // ===== PASS h: h_hat = tanh(x Wh + rh Uh + bh)
#pragma unroll
  for (int fa = 0; fa < 4; ++fa)
#pragma unroll
    for (int fb = 0; fb < 2; ++fb) acc[fa][fb] = (f32x4){0.f,0.f,0.f,0.f};
  sweep8(acc, Bh, Bh + 8192, x_l, l15, lg4);          // x half

  __syncthreads();                           // B3: all waves done reading x_l
#pragma unroll
  for (int fb = 0; fb < 2; ++fb) {           // overwrite x_l with rh (cross-thread)
    const int col = wv * 32 + fb * 16 + l15;
#pragma unroll
    for (int fa = 0; fa < 4; ++fa)
#pragma unroll
      for (int p = 0; p < 2; ++p) {
        const int row = fa * 16 + lg4 * 4 + 2 * p;
        unsigned int w = rhp[fa][fb][p];
        ldsA_put(x_l, row,     col, (unsigned short)(w & 0xffffu));
        ldsA_put(x_l, row + 1, col, (unsigned short)(w >> 16));
      }
  }
  __syncthreads();                           // B4: rh visible

  sweep8(acc, Bh + 4096, Bh + 4096 + 8192, x_l, l15, lg4);   // rh half (kt 8..15)

  // ===== final epilogue: h = z*h_prev + (1-z)*h_hat
  {
    const unsigned int* zl = (const unsigned int*)h_l;
#pragma unroll
    for (int fb = 0; fb < 2; ++fb) {
      const int col = wv * 32 + fb * 16 + l15;
      const float bv = bh[col];
#pragma unroll
      for (int fa = 0; fa < 4; ++fa) {
        f32x4 a = acc[fa][fb];
#pragma unroll
        for (int p = 0; p < 2; ++p) {
          const int rp = fa * 8 + lg4 * 2 + p;
          const unsigned int zw = zl[rp * 256 + col];
#pragma unroll
          for (int q = 0; q < 2; ++q) {
            const int row = fa * 16 + lg4 * 4 + 2 * p + q;
            const size_t oi = (size_t)(row0 + row) * 256 + col;
            const float hh = tanh_(a[2*p+q] + bv);
            const float z = bf2f((unsigned short)(q ? (zw >> 16) : (zw & 0xffffu)));
            out[oi] = z * hp[oi] + (1.0f - z) * hh;
          }
        }
      }
    }
  }
}

extern "C" void kernel_launch(void* const* d_in, const int* in_sizes, int n_in,
                              void* d_out, int out_size, void* d_ws, size_t ws_size,
                              hipStream_t stream) {
  const float* x  = (const float*)d_in[0];
  const float* hp = (const float*)d_in[1];
  const float* Wz = (const float*)d_in[2];
  const float* Uz = (const float*)d_in[3];
  const float* bz = (const float*)d_in[4];
  const float* Wr = (const float*)d_in[5];
  const float* Ur = (const float*)d_in[6];
  const float* br = (const float*)d_in[7];
  const float* Wh = (const float*)d_in[8];
  const float* Uh = (const float*)d_in[9];
  const float* bh = (const float*)d_in[10];

  if (ws_size < (size_t)(512 * 512 + 256 * 512) * sizeof(unsigned short)) return;  // need 768 KB

  unsigned short* wzr = (unsigned short*)d_ws;
  unsigned short* whh = wzr + 512 * 512;

  gru_prep<<<1536, 256, 0, stream>>>(Wz, Uz, Wr, Ur, Wh, Uh, wzr, whh);
  gru_main<<<1024, 512, 0, stream>>>(x, hp, wzr, whh, bz, br, bh, (float*)d_out);
}

// Round 14
// 120.701 us; speedup vs baseline: 1.3319x; 1.0905x over previous
//
#include <hip/hip_runtime.h>
#include <hip/hip_bf16.h>

// GRU cell v14: 32x32x16 MFMA (half the fragment traffic & instr count),
// wave tile 32x64 (acc = 2x16 = 32 AGPR), K-loop live set ~52 arch VGPR
// (fits the empirical 64-reg cap of launch_bounds(512,4) MFMA kernels).
// Pass order z -> r -> h. z parks in d_out (thread-private dwords),
// rh parks in h_l (last GEMM use), final epilogue reads h_prev from global.
// 3 barriers total. 1024 blocks x 512 thr, 64-row tiles, 64 KB LDS, 2 blk/CU.

typedef __attribute__((ext_vector_type(8)))  short s8v;            // 8 bf16 = 4 VGPR
typedef __attribute__((ext_vector_type(8)))  unsigned short us8;
typedef __attribute__((ext_vector_type(16))) float f16v;           // 32x32 acc tile
typedef __attribute__((ext_vector_type(4)))  float f4v;

__device__ __forceinline__ float bf2f(unsigned short u) {
  union { unsigned int i; float f; } c; c.i = ((unsigned int)u) << 16; return c.f;
}
__device__ __forceinline__ unsigned short f2bf(float f) {
  __hip_bfloat16 b = __float2bfloat16(f);            // RNE, pairs into v_cvt_pk_bf16_f32
  union { __hip_bfloat16 b; unsigned short u; } c; c.b = b; return c.u;
}
__device__ __forceinline__ unsigned int pk2(float lo, float hi) {
  return (unsigned int)f2bf(lo) | ((unsigned int)f2bf(hi) << 16);
}
__device__ __forceinline__ float sig_(float s)  { return 1.0f / (1.0f + __expf(-s)); }
__device__ __forceinline__ float tanh_(float s) { return 2.0f / (1.0f + __expf(-2.0f * s)) - 1.0f; }

// ---------------- weight prep: fp32 [K][N] -> bf16 32-col fragment tiles ----------------
// Tile (nt, kt) = 32 n x 16 k = 512 shorts (1 KB), lane-major:
//   n = nt*32 + (lane&31), k = kt*16 + (lane>>5)*8 + e ; tile index t = nt*32 + kt.
// wzr: nt 0..7 = Wz/Uz (cols 0..255), nt 8..15 = Wr/Ur. whh: nt 0..7 = Wh/Uh.
// k < 256 -> W[k][n], else U[k-256][n].
__global__ void gru_prep(const float* __restrict__ Wz, const float* __restrict__ Uz,
                         const float* __restrict__ Wr, const float* __restrict__ Ur,
                         const float* __restrict__ Wh, const float* __restrict__ Uh,
                         unsigned short* __restrict__ wzr, unsigned short* __restrict__ whh) {
  int idx = blockIdx.x * 256 + threadIdx.x;
  if (idx < 512 * 512) {
    int t = idx >> 9, s = idx & 511, lane = s >> 3, e = s & 7;
    int nt = t >> 5, kt = t & 31;
    int n = nt * 32 + (lane & 31);
    int k = kt * 16 + ((lane >> 5) << 3) + e;
    int nn = n & 255;
    float v;
    if (n < 256) v = (k < 256) ? Wz[k * 256 + nn] : Uz[(k - 256) * 256 + nn];
    else         v = (k < 256) ? Wr[k * 256 + nn] : Ur[(k - 256) * 256 + nn];
    wzr[idx] = f2bf(v);
  } else if (idx < 512 * 512 + 256 * 512) {
    int j = idx - 512 * 512;
    int t = j >> 9, s = j & 511, lane = s >> 3, e = s & 7;
    int nt = t >> 5, kt = t & 31;
    int n = nt * 32 + (lane & 31);
    int k = kt * 16 + ((lane >> 5) << 3) + e;
    float v = (k < 256) ? Wh[k * 256 + n] : Uh[(k - 256) * 256 + n];
    whh[j] = f2bf(v);
  }
}

// ---- K=512 sweep: 32 chunks of 16; A = x_l (c<16) then h_l (c>=16) ----
// B: ring-4 (distance-3) named double-buffer; A: software-pipelined by 1 chunk.
// b0p/b1p: lane-adjusted tile streams (chunk stride 512 shorts).
__device__ __forceinline__ void sweep32(f16v acc[2],
    const unsigned short* __restrict__ b0p, const unsigned short* __restrict__ b1p,
    const unsigned short* Ax, const unsigned short* Ah,
    int l31, int hi, int arow0)
{
  const int row = arow0 + l31;
  const int r7 = row & 7;
  const unsigned short* Abx = Ax + row * 256;
  const unsigned short* Abh = Ah + row * 256;
  s8v b[4][2];
  s8v a_cur, a_nxt;
  a_cur  = *(const s8v*)(Abx + ((hi ^ r7) * 8));                 // chunk 0 (kk=0)
  b[0][0] = *(const s8v*)(b0p);         b[0][1] = *(const s8v*)(b1p);
  b[1][0] = *(const s8v*)(b0p + 512);   b[1][1] = *(const s8v*)(b1p + 512);
  b[2][0] = *(const s8v*)(b0p + 1024);  b[2][1] = *(const s8v*)(b1p + 1024);
#pragma unroll
  for (int c = 0; c < 32; ++c) {
    if (c + 3 < 32) {
      const int s = (c + 3) & 3;
      b[s][0] = *(const s8v*)(b0p + (c + 3) * 512);
      b[s][1] = *(const s8v*)(b1p + (c + 3) * 512);
    }
    if (c + 1 < 32) {
      const int cn = c + 1;
      const unsigned short* Ab = (cn < 16) ? Abx : Abh;
      const int kk = cn & 15;
      a_nxt = *(const s8v*)(Ab + (((kk * 2 + hi) ^ r7) * 8));
    }
    __builtin_amdgcn_sched_barrier(0);
    const int s = c & 3;
    acc[0] = __builtin_amdgcn_mfma_f32_32x32x16_bf16(a_cur, b[s][0], acc[0], 0, 0, 0);
    acc[1] = __builtin_amdgcn_mfma_f32_32x32x16_bf16(a_cur, b[s][1], acc[1], 0, 0, 0);
    __builtin_amdgcn_sched_barrier(0);
    a_cur = a_nxt;
  }
}

// swizzled scalar LDS accessors (granule-XOR layout)
__device__ __forceinline__ float ldsA_get(const unsigned short* A, int row, int col) {
  int gp = ((col >> 3) ^ (row & 7));
  return bf2f(A[row * 256 + gp * 8 + (col & 7)]);
}
__device__ __forceinline__ void ldsA_put(unsigned short* A, int row, int col, unsigned short v) {
  int gp = ((col >> 3) ^ (row & 7));
  A[row * 256 + gp * 8 + (col & 7)] = v;
}

// C-tile row for reg q (m74/m101 verified): (q&3) + 8*(q>>2) + 4*hi
#define CROW(q, hi) (((q) & 3) + 8 * ((q) >> 2) + 4 * (hi))

// ---------------- main fused kernel: 64 rows per block, 8 waves ----------------
__global__ __launch_bounds__(512, 4) void gru_main(
    const float* __restrict__ x, const float* __restrict__ hp,
    const unsigned short* __restrict__ wzr, const unsigned short* __restrict__ whh,
    const float* __restrict__ bz, const float* __restrict__ br, const float* __restrict__ bh,
    float* __restrict__ out)
{
  __shared__ __align__(16) unsigned short x_l[64 * 256];   // 32 KB; x (bf16, XOR layout)
  __shared__ __align__(16) unsigned short h_l[64 * 256];   // 32 KB; h_prev, later rh

  const int tid = threadIdx.x;
  const int lane = tid & 63;
  const int wv = tid >> 6;                   // 0..7
  const int wr = wv >> 2;                    // 0..1 : 32-row slice
  const int wc = wv & 3;                     // 0..3 : 64-col slice
  const int l31 = lane & 31, hi = lane >> 5;
  const int row0 = blockIdx.x * 64;

  // B tile streams (nt stride 16384 shorts = 32 chunks x 512)
  const unsigned short* Bz = wzr + (size_t)(wc * 2) * 16384 + lane * 8;
  const unsigned short* Br = wzr + 131072 + (size_t)(wc * 2) * 16384 + lane * 8;
  const unsigned short* Bh = whh + (size_t)(wc * 2) * 16384 + lane * 8;

  unsigned int* outw = (unsigned int*)out;

  // ---- stage x, h tiles to LDS (fp32 -> bf16), granule-XOR layout
  {
    const int srow = tid >> 3;               // 0..63
    const int part = tid & 7;                // 4 granules each
    const float* xs = x  + (size_t)(row0 + srow) * 256 + part * 32;
    const float* hs = hp + (size_t)(row0 + srow) * 256 + part * 32;
    unsigned short* xd = x_l + srow * 256;
    unsigned short* hd = h_l + srow * 256;
    const int r7 = srow & 7;
#pragma unroll
    for (int j = 0; j < 4; ++j) {
      int gp = (part * 4 + j) ^ r7;
      f4v v0 = *(const f4v*)(xs + j * 8);
      f4v v1 = *(const f4v*)(xs + j * 8 + 4);
      us8 o;
      o[0]=f2bf(v0[0]); o[1]=f2bf(v0[1]); o[2]=f2bf(v0[2]); o[3]=f2bf(v0[3]);
      o[4]=f2bf(v1[0]); o[5]=f2bf(v1[1]); o[6]=f2bf(v1[2]); o[7]=f2bf(v1[3]);
      *(us8*)(xd + gp * 8) = o;
    }
#pragma unroll
    for (int j = 0; j < 4; ++j) {
      int gp = (part * 4 + j) ^ r7;
      f4v v0 = *(const f4v*)(hs + j * 8);
      f4v v1 = *(const f4v*)(hs + j * 8 + 4);
      us8 o;
      o[0]=f2bf(v0[0]); o[1]=f2bf(v0[1]); o[2]=f2bf(v0[2]); o[3]=f2bf(v0[3]);
      o[4]=f2bf(v1[0]); o[5]=f2bf(v1[1]); o[6]=f2bf(v1[2]); o[7]=f2bf(v1[3]);
      *(us8*)(hd + gp * 8) = o;
    }
  }
  __syncthreads();                           // B1

  f16v acc[2];

  // ===== PASS z: z = sigmoid(x Wz + h Uz + bz) -> parked in d_out (thread-private dwords)
  acc[0] = (f16v)(0.f); acc[1] = (f16v)(0.f);
  sweep32(acc, Bz, Bz + 16384, x_l, h_l, l31, hi, wr * 32);
#pragma unroll
  for (int fb = 0; fb < 2; ++fb) {
    const int col = wc * 64 + fb * 32 + l31;
    const float bv = bz[col];
#pragma unroll
    for (int qq = 0; qq < 8; ++qq) {
      const int q0 = 2 * qq;
      const int r0 = wr * 32 + CROW(q0, hi);
      outw[(size_t)(row0 + r0) * 256 + col] =
          pk2(sig_(acc[fb][q0] + bv), sig_(acc[fb][q0 + 1] + bv));
    }
  }

  // ===== PASS r: r = sigmoid(x Wr + h Ur + br); rh = r * h_prev -> parked in h_l
  acc[0] = (f16v)(0.f); acc[1] = (f16v)(0.f);
  sweep32(acc, Br, Br + 16384, x_l, h_l, l31, hi, wr * 32);
  {
    unsigned int rhp[2][8];                  // transient 16 VGPR (spans one barrier)
#pragma unroll
    for (int fb = 0; fb < 2; ++fb) {
      const int col = wc * 64 + fb * 32 + l31;
      const float bv = br[col];
#pragma unroll
      for (int qq = 0; qq < 8; ++qq) {
        const int q0 = 2 * qq;
        const int r0 = wr * 32 + CROW(q0, hi);
        const float rr0 = sig_(acc[fb][q0]     + bv) * ldsA_get(h_l, r0,     col);
        const float rr1 = sig_(acc[fb][q0 + 1] + bv) * ldsA_get(h_l, r0 + 1, col);
        rhp[fb][qq] = pk2(rr0, rr1);
      }
    }
    __syncthreads();                         // B2: all h_l GEMM/epilogue reads done
#pragma unroll
    for (int fb = 0; fb < 2; ++fb) {
      const int col = wc * 64 + fb * 32 + l31;
#pragma unroll
      for (int qq = 0; qq < 8; ++qq) {
        const int q0 = 2 * qq;
        const int r0 = wr * 32 + CROW(q0, hi);
        const unsigned int w = rhp[fb][qq];
        ldsA_put(h_l, r0,     col, (unsigned short)(w & 0xffffu));
        ldsA_put(h_l, r0 + 1, col, (unsigned short)(w >> 16));
      }
    }
  }
  __syncthreads();                           // B3: rh visible to all waves

  // ===== PASS h: h_hat = tanh(x Wh + rh Uh + bh); h_l now holds rh
  acc[0] = (f16v)(0.f); acc[1] = (f16v)(0.f);
  sweep32(acc, Bh, Bh + 16384, x_l, h_l, l31, hi, wr * 32);

  // ===== final epilogue: h = z*h_prev + (1-z)*h_hat (z from d_out, h_prev from global)
#pragma unroll
  for (int fb = 0; fb < 2; ++fb) {
    const int col = wc * 64 + fb * 32 + l31;
    const float bv = bh[col];
#pragma unroll
    for (int qq = 0; qq < 8; ++qq) {
      const int q0 = 2 * qq;
      const int r0 = wr * 32 + CROW(q0, hi);
      const unsigned int zw = outw[(size_t)(row0 + r0) * 256 + col];
#pragma unroll
      for (int j = 0; j < 2; ++j) {
        const int row = r0 + j;
        const size_t oi = (size_t)(row0 + row) * 256 + col;
        const float hh = tanh_(acc[fb][q0 + j] + bv);
        const float z = bf2f((unsigned short)(j ? (zw >> 16) : (zw & 0xffffu)));
        out[oi] = z * hp[oi] + (1.0f - z) * hh;
      }
    }
  }
}

extern "C" void kernel_launch(void* const* d_in, const int* in_sizes, int n_in,
                              void* d_out, int out_size, void* d_ws, size_t ws_size,
                              hipStream_t stream) {
  const float* x  = (const float*)d_in[0];
  const float* hp = (const float*)d_in[1];
  const float* Wz = (const float*)d_in[2];
  const float* Uz = (const float*)d_in[3];
  const float* bz = (const float*)d_in[4];
  const float* Wr = (const float*)d_in[5];
  const float* Ur = (const float*)d_in[6];
  const float* br = (const float*)d_in[7];
  const float* Wh = (const float*)d_in[8];
  const float* Uh = (const float*)d_in[9];
  const float* bh = (const float*)d_in[10];

  if (ws_size < (size_t)(512 * 512 + 256 * 512) * sizeof(unsigned short)) return;  // need 768 KB

  unsigned short* wzr = (unsigned short*)d_ws;
  unsigned short* whh = wzr + 512 * 512;

  gru_prep<<<1536, 256, 0, stream>>>(Wz, Uz, Wr, Ur, Wh, Uh, wzr, whh);
  gru_main<<<1024, 512, 0, stream>>>(x, hp, wzr, whh, bz, br, bh, (float*)d_out);
}

// Round 15
// 97.190 us; speedup vs baseline: 1.6541x; 1.2419x over previous
//
#include <hip/hip_runtime.h>
#include <hip/hip_bf16.h>

// GRU cell v15: 32x32x16 MFMA, wave tile 64x64 (acc = 4x16 = 64 regs), 4 waves
// per 256-thr block, 64-row tiles, 64 KB LDS -> 2 blocks/CU, launch_bounds(256,2)
// -> 256-reg budget (first config with true register headroom).
// NO B-stream duplication (each wave owns 64 distinct cols) and halved A-LDS
// traffic per MFMA. Pass order z -> r -> h; z parks in d_out (thread-private
// dwords), rh parks in h_l in place; 3 barriers total; h_prev re-read from
// global in epilogues. B ring-4 (distance-3) + A distance-1 pipelines, fenced.

typedef __attribute__((ext_vector_type(8)))  short s8v;            // 8 bf16 = 4 VGPR
typedef __attribute__((ext_vector_type(8)))  unsigned short us8;
typedef __attribute__((ext_vector_type(16))) float f16v;           // 32x32 acc tile
typedef __attribute__((ext_vector_type(4)))  float f4v;

__device__ __forceinline__ float bf2f(unsigned short u) {
  union { unsigned int i; float f; } c; c.i = ((unsigned int)u) << 16; return c.f;
}
__device__ __forceinline__ unsigned short f2bf(float f) {
  __hip_bfloat16 b = __float2bfloat16(f);            // RNE, pairs into v_cvt_pk_bf16_f32
  union { __hip_bfloat16 b; unsigned short u; } c; c.b = b; return c.u;
}
__device__ __forceinline__ unsigned int pk2(float lo, float hi) {
  return (unsigned int)f2bf(lo) | ((unsigned int)f2bf(hi) << 16);
}
__device__ __forceinline__ float sig_(float s)  { return 1.0f / (1.0f + __expf(-s)); }
__device__ __forceinline__ float tanh_(float s) { return 2.0f / (1.0f + __expf(-2.0f * s)) - 1.0f; }

// ---------------- weight prep: fp32 [K][N] -> bf16 32-col fragment tiles ----------------
// Tile (nt, kt) = 32 n x 16 k = 512 shorts (1 KB), lane-major:
//   n = nt*32 + (lane&31), k = kt*16 + (lane>>5)*8 + e ; tile index t = nt*32 + kt.
// wzr: nt 0..7 = Wz/Uz, nt 8..15 = Wr/Ur. whh: nt 0..7 = Wh/Uh. k<256 -> W, else U.
__global__ void gru_prep(const float* __restrict__ Wz, const float* __restrict__ Uz,
                         const float* __restrict__ Wr, const float* __restrict__ Ur,
                         const float* __restrict__ Wh, const float* __restrict__ Uh,
                         unsigned short* __restrict__ wzr, unsigned short* __restrict__ whh) {
  int idx = blockIdx.x * 256 + threadIdx.x;
  if (idx < 512 * 512) {
    int t = idx >> 9, s = idx & 511, lane = s >> 3, e = s & 7;
    int nt = t >> 5, kt = t & 31;
    int n = nt * 32 + (lane & 31);
    int k = kt * 16 + ((lane >> 5) << 3) + e;
    int nn = n & 255;
    float v;
    if (n < 256) v = (k < 256) ? Wz[k * 256 + nn] : Uz[(k - 256) * 256 + nn];
    else         v = (k < 256) ? Wr[k * 256 + nn] : Ur[(k - 256) * 256 + nn];
    wzr[idx] = f2bf(v);
  } else if (idx < 512 * 512 + 256 * 512) {
    int j = idx - 512 * 512;
    int t = j >> 9, s = j & 511, lane = s >> 3, e = s & 7;
    int nt = t >> 5, kt = t & 31;
    int n = nt * 32 + (lane & 31);
    int k = kt * 16 + ((lane >> 5) << 3) + e;
    float v = (k < 256) ? Wh[k * 256 + n] : Uh[(k - 256) * 256 + n];
    whh[j] = f2bf(v);
  }
}

#define MFMA32(a, b, c) __builtin_amdgcn_mfma_f32_32x32x16_bf16((a), (b), (c), 0, 0, 0)

// ---- K=512 sweep: 32 chunks of 16; A = x_l (c<16) then h_l (c>=16) ----
// 64x64 wave tile: 2 A-frags (rows l31, 32+l31) x 2 B-frags -> 4 MFMA/chunk.
// B: ring-4 distance-3 ; A: distance-1. All indices static; fenced.
__device__ __forceinline__ void sweep32(f16v acc[2][2],
    const unsigned short* __restrict__ b0p, const unsigned short* __restrict__ b1p,
    const unsigned short* Ax, const unsigned short* Ah, int l31, int hi)
{
  const int r7 = l31 & 7;                    // rows l31 and 32+l31 share (row&7)
  const unsigned short* Ax0 = Ax + l31 * 256;
  const unsigned short* Ax1 = Ax + (32 + l31) * 256;
  const unsigned short* Ah0 = Ah + l31 * 256;
  const unsigned short* Ah1 = Ah + (32 + l31) * 256;
  s8v b[4][2];
  s8v a0c, a1c, a0n, a1n;
  a0c = *(const s8v*)(Ax0 + ((hi ^ r7) * 8));
  a1c = *(const s8v*)(Ax1 + ((hi ^ r7) * 8));
  b[0][0] = *(const s8v*)(b0p);         b[0][1] = *(const s8v*)(b1p);
  b[1][0] = *(const s8v*)(b0p + 512);   b[1][1] = *(const s8v*)(b1p + 512);
  b[2][0] = *(const s8v*)(b0p + 1024);  b[2][1] = *(const s8v*)(b1p + 1024);
#pragma unroll
  for (int c = 0; c < 32; ++c) {
    if (c + 3 < 32) {
      const int s = (c + 3) & 3;
      b[s][0] = *(const s8v*)(b0p + (c + 3) * 512);
      b[s][1] = *(const s8v*)(b1p + (c + 3) * 512);
    }
    if (c + 1 < 32) {
      const int cn = c + 1;
      const int kk = cn & 15;
      const int gp = ((kk * 2 + hi) ^ r7) * 8;
      if (cn < 16) { a0n = *(const s8v*)(Ax0 + gp); a1n = *(const s8v*)(Ax1 + gp); }
      else         { a0n = *(const s8v*)(Ah0 + gp); a1n = *(const s8v*)(Ah1 + gp); }
    }
    __builtin_amdgcn_sched_barrier(0);
    const int s = c & 3;
    acc[0][0] = MFMA32(a0c, b[s][0], acc[0][0]);
    acc[0][1] = MFMA32(a0c, b[s][1], acc[0][1]);
    acc[1][0] = MFMA32(a1c, b[s][0], acc[1][0]);
    acc[1][1] = MFMA32(a1c, b[s][1], acc[1][1]);
    __builtin_amdgcn_sched_barrier(0);
    a0c = a0n; a1c = a1n;
  }
}

// swizzled scalar LDS accessors (granule-XOR layout)
__device__ __forceinline__ float ldsA_get(const unsigned short* A, int row, int col) {
  int gp = ((col >> 3) ^ (row & 7));
  return bf2f(A[row * 256 + gp * 8 + (col & 7)]);
}
__device__ __forceinline__ void ldsA_put(unsigned short* A, int row, int col, unsigned short v) {
  int gp = ((col >> 3) ^ (row & 7));
  A[row * 256 + gp * 8 + (col & 7)] = v;
}

// C-tile row for reg q (m74/m101 verified): (q&3) + 8*(q>>2) + 4*hi
#define CROW(q, hi) (((q) & 3) + 8 * ((q) >> 2) + 4 * (hi))

// ---------------- main fused kernel: 64 rows per block, 4 waves ----------------
__global__ __launch_bounds__(256, 2) void gru_main(
    const float* __restrict__ x, const float* __restrict__ hp,
    const unsigned short* __restrict__ wzr, const unsigned short* __restrict__ whh,
    const float* __restrict__ bz, const float* __restrict__ br, const float* __restrict__ bh,
    float* __restrict__ out)
{
  __shared__ __align__(16) unsigned short x_l[64 * 256];   // 32 KB; x (bf16, XOR layout)
  __shared__ __align__(16) unsigned short h_l[64 * 256];   // 32 KB; h_prev, later rh

  const int tid = threadIdx.x;
  const int lane = tid & 63;
  const int wv = tid >> 6;                   // 0..3 : wave's 64-col slice
  const int l31 = lane & 31, hi = lane >> 5;
  const int row0 = blockIdx.x * 64;

  // B tile streams (nt stride 16384 shorts = 32 chunks x 512); wave owns nt wv*2, wv*2+1
  const unsigned short* Bz = wzr + (size_t)(wv * 2) * 16384 + lane * 8;
  const unsigned short* Br = wzr + 131072 + (size_t)(wv * 2) * 16384 + lane * 8;
  const unsigned short* Bh = whh + (size_t)(wv * 2) * 16384 + lane * 8;

  unsigned int* outw = (unsigned int*)out;

  // ---- stage x, h tiles to LDS (fp32 -> bf16), granule-XOR layout; 64 elems/thread/array
  {
    const int srow = tid >> 2;               // 0..63
    const int part = tid & 3;                // 64 cols = 8 granules each
    const float* xs = x  + (size_t)(row0 + srow) * 256 + part * 64;
    const float* hs = hp + (size_t)(row0 + srow) * 256 + part * 64;
    unsigned short* xd = x_l + srow * 256;
    unsigned short* hd = h_l + srow * 256;
    const int r7 = srow & 7;
#pragma unroll
    for (int j = 0; j < 8; ++j) {
      int gp = (part * 8 + j) ^ r7;
      f4v v0 = *(const f4v*)(xs + j * 8);
      f4v v1 = *(const f4v*)(xs + j * 8 + 4);
      us8 o;
      o[0]=f2bf(v0[0]); o[1]=f2bf(v0[1]); o[2]=f2bf(v0[2]); o[3]=f2bf(v0[3]);
      o[4]=f2bf(v1[0]); o[5]=f2bf(v1[1]); o[6]=f2bf(v1[2]); o[7]=f2bf(v1[3]);
      *(us8*)(xd + gp * 8) = o;
    }
#pragma unroll
    for (int j = 0; j < 8; ++j) {
      int gp = (part * 8 + j) ^ r7;
      f4v v0 = *(const f4v*)(hs + j * 8);
      f4v v1 = *(const f4v*)(hs + j * 8 + 4);
      us8 o;
      o[0]=f2bf(v0[0]); o[1]=f2bf(v0[1]); o[2]=f2bf(v0[2]); o[3]=f2bf(v0[3]);
      o[4]=f2bf(v1[0]); o[5]=f2bf(v1[1]); o[6]=f2bf(v1[2]); o[7]=f2bf(v1[3]);
      *(us8*)(hd + gp * 8) = o;
    }
  }
  __syncthreads();                           // B1

  f16v acc[2][2];

  // ===== PASS z: z = sigmoid(x Wz + h Uz + bz) -> parked in d_out (thread-private dwords)
  acc[0][0] = (f16v)(0.f); acc[0][1] = (f16v)(0.f);
  acc[1][0] = (f16v)(0.f); acc[1][1] = (f16v)(0.f);
  sweep32(acc, Bz, Bz + 16384, x_l, h_l, l31, hi);
#pragma unroll
  for (int fa = 0; fa < 2; ++fa)
#pragma unroll
    for (int fb = 0; fb < 2; ++fb) {
      const int col = wv * 64 + fb * 32 + l31;
      const float bv = bz[col];
#pragma unroll
      for (int qq = 0; qq < 8; ++qq) {
        const int q0 = 2 * qq;
        const int r0 = fa * 32 + CROW(q0, hi);
        outw[(size_t)(row0 + r0) * 256 + col] =
            pk2(sig_(acc[fa][fb][q0] + bv), sig_(acc[fa][fb][q0 + 1] + bv));
      }
    }

  // ===== PASS r: r = sigmoid(x Wr + h Ur + br); rh = r * h_prev -> parked in h_l
  acc[0][0] = (f16v)(0.f); acc[0][1] = (f16v)(0.f);
  acc[1][0] = (f16v)(0.f); acc[1][1] = (f16v)(0.f);
  sweep32(acc, Br, Br + 16384, x_l, h_l, l31, hi);
  {
    unsigned int rhp[2][2][8];               // transient 32 VGPR (spans one barrier)
#pragma unroll
    for (int fa = 0; fa < 2; ++fa)
#pragma unroll
      for (int fb = 0; fb < 2; ++fb) {
        const int col = wv * 64 + fb * 32 + l31;
        const float bv = br[col];
#pragma unroll
        for (int qq = 0; qq < 8; ++qq) {
          const int q0 = 2 * qq;
          const int r0 = fa * 32 + CROW(q0, hi);
          const float rr0 = sig_(acc[fa][fb][q0]     + bv) * ldsA_get(h_l, r0,     col);
          const float rr1 = sig_(acc[fa][fb][q0 + 1] + bv) * ldsA_get(h_l, r0 + 1, col);
          rhp[fa][fb][qq] = pk2(rr0, rr1);
        }
      }
    __syncthreads();                         // B2: all z/r GEMM + epilogue reads of h_l done
#pragma unroll
    for (int fa = 0; fa < 2; ++fa)
#pragma unroll
      for (int fb = 0; fb < 2; ++fb) {
        const int col = wv * 64 + fb * 32 + l31;
#pragma unroll
        for (int qq = 0; qq < 8; ++qq) {
          const int q0 = 2 * qq;
          const int r0 = fa * 32 + CROW(q0, hi);
          const unsigned int w = rhp[fa][fb][qq];
          ldsA_put(h_l, r0,     col, (unsigned short)(w & 0xffffu));
          ldsA_put(h_l, r0 + 1, col, (unsigned short)(w >> 16));
        }
      }
  }
  __syncthreads();                           // B3: rh visible to all waves

  // ===== PASS h: h_hat = tanh(x Wh + rh Uh + bh); h_l now holds rh
  acc[0][0] = (f16v)(0.f); acc[0][1] = (f16v)(0.f);
  acc[1][0] = (f16v)(0.f); acc[1][1] = (f16v)(0.f);
  sweep32(acc, Bh, Bh + 16384, x_l, h_l, l31, hi);

  // ===== final epilogue: h = z*h_prev + (1-z)*h_hat (z from d_out, h_prev from global)
#pragma unroll
  for (int fa = 0; fa < 2; ++fa)
#pragma unroll
    for (int fb = 0; fb < 2; ++fb) {
      const int col = wv * 64 + fb * 32 + l31;
      const float bv = bh[col];
#pragma unroll
      for (int qq = 0; qq < 8; ++qq) {
        const int q0 = 2 * qq;
        const int r0 = fa * 32 + CROW(q0, hi);
        const unsigned int zw = outw[(size_t)(row0 + r0) * 256 + col];
#pragma unroll
        for (int j = 0; j < 2; ++j) {
          const int row = r0 + j;
          const size_t oi = (size_t)(row0 + row) * 256 + col;
          const float hh = tanh_(acc[fa][fb][q0 + j] + bv);
          const float z = bf2f((unsigned short)(j ? (zw >> 16) : (zw & 0xffffu)));
          out[oi] = z * hp[oi] + (1.0f - z) * hh;
        }
      }
    }
}

extern "C" void kernel_launch(void* const* d_in, const int* in_sizes, int n_in,
                              void* d_out, int out_size, void* d_ws, size_t ws_size,
                              hipStream_t stream) {
  const float* x  = (const float*)d_in[0];
  const float* hp = (const float*)d_in[1];
  const float* Wz = (const float*)d_in[2];
  const float* Uz = (const float*)d_in[3];
  const float* bz = (const float*)d_in[4];
  const float* Wr = (const float*)d_in[5];
  const float* Ur = (const float*)d_in[6];
  const float* br = (const float*)d_in[7];
  const float* Wh = (const float*)d_in[8];
  const float* Uh = (const float*)d_in[9];
  const float* bh = (const float*)d_in[10];

  if (ws_size < (size_t)(512 * 512 + 256 * 512) * sizeof(unsigned short)) return;  // need 768 KB

  unsigned short* wzr = (unsigned short*)d_ws;
  unsigned short* whh = wzr + 512 * 512;

  gru_prep<<<1536, 256, 0, stream>>>(Wz, Uz, Wr, Ur, Wh, Uh, wzr, whh);
  gru_main<<<1024, 256, 0, stream>>>(x, hp, wzr, whh, bz, br, bh, (float*)d_out);
}

// Round 16
// 90.300 us; speedup vs baseline: 1.7804x; 1.0763x over previous
//
#include <hip/hip_runtime.h>
#include <hip/hip_bf16.h>

// GRU cell v16: v15 structure (32x32x16 MFMA, wave tile 64x64, 4 waves/256 thr,
// 64-row tiles, 64 KB LDS, 2 blocks/CU, (256,2) -> 256-reg budget) with:
//  - B ring-6 / distance-5 prefetch (covers L2 latency ~250 cyc)
//  - A triple-buffer / distance-2 (covers LDS latency ~120 cyc)
//  - z gate held in registers (32 VGPR) -> no d_out park round-trip
// Pass order z -> r -> h; rh parks in h_l in place; 3 barriers total.

typedef __attribute__((ext_vector_type(8)))  short s8v;            // 8 bf16 = 4 VGPR
typedef __attribute__((ext_vector_type(8)))  unsigned short us8;
typedef __attribute__((ext_vector_type(16))) float f16v;           // 32x32 acc tile
typedef __attribute__((ext_vector_type(4)))  float f4v;

__device__ __forceinline__ float bf2f(unsigned short u) {
  union { unsigned int i; float f; } c; c.i = ((unsigned int)u) << 16; return c.f;
}
__device__ __forceinline__ unsigned short f2bf(float f) {
  __hip_bfloat16 b = __float2bfloat16(f);            // RNE, pairs into v_cvt_pk_bf16_f32
  union { __hip_bfloat16 b; unsigned short u; } c; c.b = b; return c.u;
}
__device__ __forceinline__ unsigned int pk2(float lo, float hi) {
  return (unsigned int)f2bf(lo) | ((unsigned int)f2bf(hi) << 16);
}
__device__ __forceinline__ float sig_(float s)  { return 1.0f / (1.0f + __expf(-s)); }
__device__ __forceinline__ float tanh_(float s) { return 2.0f / (1.0f + __expf(-2.0f * s)) - 1.0f; }

// ---------------- weight prep: fp32 [K][N] -> bf16 32-col fragment tiles ----------------
// Tile (nt, kt) = 32 n x 16 k = 512 shorts (1 KB), lane-major:
//   n = nt*32 + (lane&31), k = kt*16 + (lane>>5)*8 + e ; tile index t = nt*32 + kt.
// wzr: nt 0..7 = Wz/Uz, nt 8..15 = Wr/Ur. whh: nt 0..7 = Wh/Uh. k<256 -> W, else U.
__global__ void gru_prep(const float* __restrict__ Wz, const float* __restrict__ Uz,
                         const float* __restrict__ Wr, const float* __restrict__ Ur,
                         const float* __restrict__ Wh, const float* __restrict__ Uh,
                         unsigned short* __restrict__ wzr, unsigned short* __restrict__ whh) {
  int idx = blockIdx.x * 256 + threadIdx.x;
  if (idx < 512 * 512) {
    int t = idx >> 9, s = idx & 511, lane = s >> 3, e = s & 7;
    int nt = t >> 5, kt = t & 31;
    int n = nt * 32 + (lane & 31);
    int k = kt * 16 + ((lane >> 5) << 3) + e;
    int nn = n & 255;
    float v;
    if (n < 256) v = (k < 256) ? Wz[k * 256 + nn] : Uz[(k - 256) * 256 + nn];
    else         v = (k < 256) ? Wr[k * 256 + nn] : Ur[(k - 256) * 256 + nn];
    wzr[idx] = f2bf(v);
  } else if (idx < 512 * 512 + 256 * 512) {
    int j = idx - 512 * 512;
    int t = j >> 9, s = j & 511, lane = s >> 3, e = s & 7;
    int nt = t >> 5, kt = t & 31;
    int n = nt * 32 + (lane & 31);
    int k = kt * 16 + ((lane >> 5) << 3) + e;
    float v = (k < 256) ? Wh[k * 256 + n] : Uh[(k - 256) * 256 + n];
    whh[j] = f2bf(v);
  }
}

#define MFMA32(a, b, c) __builtin_amdgcn_mfma_f32_32x32x16_bf16((a), (b), (c), 0, 0, 0)

// ---- K=512 sweep: 32 chunks of 16; A = x_l (c<16) then h_l (c>=16) ----
// B: ring-6 distance-5 ; A: ring-3 distance-2. All indices static; fenced.
__device__ __forceinline__ void sweep32(f16v acc[2][2],
    const unsigned short* __restrict__ b0p, const unsigned short* __restrict__ b1p,
    const unsigned short* Ax, const unsigned short* Ah, int l31, int hi)
{
  const int r7 = l31 & 7;                    // rows l31 and 32+l31 share (row&7)
  const unsigned short* Ax0 = Ax + l31 * 256;
  const unsigned short* Ax1 = Ax + (32 + l31) * 256;
  const unsigned short* Ah0 = Ah + l31 * 256;
  const unsigned short* Ah1 = Ah + (32 + l31) * 256;
  s8v b[6][2];
  s8v a[3][2];
#pragma unroll
  for (int i = 0; i < 5; ++i) {
    b[i][0] = *(const s8v*)(b0p + i * 512);
    b[i][1] = *(const s8v*)(b1p + i * 512);
  }
  a[0][0] = *(const s8v*)(Ax0 + ((0 + hi) ^ r7) * 8);
  a[0][1] = *(const s8v*)(Ax1 + ((0 + hi) ^ r7) * 8);
  a[1][0] = *(const s8v*)(Ax0 + ((2 + hi) ^ r7) * 8);
  a[1][1] = *(const s8v*)(Ax1 + ((2 + hi) ^ r7) * 8);
#pragma unroll
  for (int c = 0; c < 32; ++c) {
    if (c + 5 < 32) {
      const int s = (c + 5) % 6;
      b[s][0] = *(const s8v*)(b0p + (c + 5) * 512);
      b[s][1] = *(const s8v*)(b1p + (c + 5) * 512);
    }
    if (c + 2 < 32) {
      const int cn = c + 2;
      const int kk = cn & 15;
      const int gp = ((kk * 2 + hi) ^ r7) * 8;
      const int s = cn % 3;
      if (cn < 16) { a[s][0] = *(const s8v*)(Ax0 + gp); a[s][1] = *(const s8v*)(Ax1 + gp); }
      else         { a[s][0] = *(const s8v*)(Ah0 + gp); a[s][1] = *(const s8v*)(Ah1 + gp); }
    }
    __builtin_amdgcn_sched_barrier(0);
    const int sb = c % 6, sa = c % 3;
    acc[0][0] = MFMA32(a[sa][0], b[sb][0], acc[0][0]);
    acc[0][1] = MFMA32(a[sa][0], b[sb][1], acc[0][1]);
    acc[1][0] = MFMA32(a[sa][1], b[sb][0], acc[1][0]);
    acc[1][1] = MFMA32(a[sa][1], b[sb][1], acc[1][1]);
    __builtin_amdgcn_sched_barrier(0);
  }
}

// swizzled scalar LDS accessors (granule-XOR layout)
__device__ __forceinline__ float ldsA_get(const unsigned short* A, int row, int col) {
  int gp = ((col >> 3) ^ (row & 7));
  return bf2f(A[row * 256 + gp * 8 + (col & 7)]);
}
__device__ __forceinline__ void ldsA_put(unsigned short* A, int row, int col, unsigned short v) {
  int gp = ((col >> 3) ^ (row & 7));
  A[row * 256 + gp * 8 + (col & 7)] = v;
}

// C-tile row for reg q (m74/m101 verified): (q&3) + 8*(q>>2) + 4*hi
#define CROW(q, hi) (((q) & 3) + 8 * ((q) >> 2) + 4 * (hi))

// ---------------- main fused kernel: 64 rows per block, 4 waves ----------------
__global__ __launch_bounds__(256, 2) void gru_main(
    const float* __restrict__ x, const float* __restrict__ hp,
    const unsigned short* __restrict__ wzr, const unsigned short* __restrict__ whh,
    const float* __restrict__ bz, const float* __restrict__ br, const float* __restrict__ bh,
    float* __restrict__ out)
{
  __shared__ __align__(16) unsigned short x_l[64 * 256];   // 32 KB; x (bf16, XOR layout)
  __shared__ __align__(16) unsigned short h_l[64 * 256];   // 32 KB; h_prev, later rh

  const int tid = threadIdx.x;
  const int lane = tid & 63;
  const int wv = tid >> 6;                   // 0..3 : wave's 64-col slice
  const int l31 = lane & 31, hi = lane >> 5;
  const int row0 = blockIdx.x * 64;

  // B tile streams (nt stride 16384 shorts = 32 chunks x 512); wave owns nt wv*2, wv*2+1
  const unsigned short* Bz = wzr + (size_t)(wv * 2) * 16384 + lane * 8;
  const unsigned short* Br = wzr + 131072 + (size_t)(wv * 2) * 16384 + lane * 8;
  const unsigned short* Bh = whh + (size_t)(wv * 2) * 16384 + lane * 8;

  // ---- stage x, h tiles to LDS (fp32 -> bf16), granule-XOR layout; 64 elems/thread/array
  {
    const int srow = tid >> 2;               // 0..63
    const int part = tid & 3;                // 64 cols = 8 granules each
    const float* xs = x  + (size_t)(row0 + srow) * 256 + part * 64;
    const float* hs = hp + (size_t)(row0 + srow) * 256 + part * 64;
    unsigned short* xd = x_l + srow * 256;
    unsigned short* hd = h_l + srow * 256;
    const int r7 = srow & 7;
#pragma unroll
    for (int j = 0; j < 8; ++j) {
      int gp = (part * 8 + j) ^ r7;
      f4v v0 = *(const f4v*)(xs + j * 8);
      f4v v1 = *(const f4v*)(xs + j * 8 + 4);
      us8 o;
      o[0]=f2bf(v0[0]); o[1]=f2bf(v0[1]); o[2]=f2bf(v0[2]); o[3]=f2bf(v0[3]);
      o[4]=f2bf(v1[0]); o[5]=f2bf(v1[1]); o[6]=f2bf(v1[2]); o[7]=f2bf(v1[3]);
      *(us8*)(xd + gp * 8) = o;
    }
#pragma unroll
    for (int j = 0; j < 8; ++j) {
      int gp = (part * 8 + j) ^ r7;
      f4v v0 = *(const f4v*)(hs + j * 8);
      f4v v1 = *(const f4v*)(hs + j * 8 + 4);
      us8 o;
      o[0]=f2bf(v0[0]); o[1]=f2bf(v0[1]); o[2]=f2bf(v0[2]); o[3]=f2bf(v0[3]);
      o[4]=f2bf(v1[0]); o[5]=f2bf(v1[1]); o[6]=f2bf(v1[2]); o[7]=f2bf(v1[3]);
      *(us8*)(hd + gp * 8) = o;
    }
  }
  __syncthreads();                           // B1

  f16v acc[2][2];
  unsigned int zp[2][2][8];                  // z gate, packed bf16 : 32 VGPR (we have budget)

  // ===== PASS z: z = sigmoid(x Wz + h Uz + bz) -> zp (registers)
  acc[0][0] = (f16v)(0.f); acc[0][1] = (f16v)(0.f);
  acc[1][0] = (f16v)(0.f); acc[1][1] = (f16v)(0.f);
  sweep32(acc, Bz, Bz + 16384, x_l, h_l, l31, hi);
#pragma unroll
  for (int fa = 0; fa < 2; ++fa)
#pragma unroll
    for (int fb = 0; fb < 2; ++fb) {
      const int col = wv * 64 + fb * 32 + l31;
      const float bv = bz[col];
#pragma unroll
      for (int qq = 0; qq < 8; ++qq) {
        const int q0 = 2 * qq;
        zp[fa][fb][qq] = pk2(sig_(acc[fa][fb][q0] + bv), sig_(acc[fa][fb][q0 + 1] + bv));
      }
    }

  // ===== PASS r: r = sigmoid(x Wr + h Ur + br); rh = r * h_prev -> parked in h_l
  acc[0][0] = (f16v)(0.f); acc[0][1] = (f16v)(0.f);
  acc[1][0] = (f16v)(0.f); acc[1][1] = (f16v)(0.f);
  sweep32(acc, Br, Br + 16384, x_l, h_l, l31, hi);
  {
    unsigned int rhp[2][2][8];               // transient 32 VGPR (spans one barrier)
#pragma unroll
    for (int fa = 0; fa < 2; ++fa)
#pragma unroll
      for (int fb = 0; fb < 2; ++fb) {
        const int col = wv * 64 + fb * 32 + l31;
        const float bv = br[col];
#pragma unroll
        for (int qq = 0; qq < 8; ++qq) {
          const int q0 = 2 * qq;
          const int r0 = fa * 32 + CROW(q0, hi);
          const float rr0 = sig_(acc[fa][fb][q0]     + bv) * ldsA_get(h_l, r0,     col);
          const float rr1 = sig_(acc[fa][fb][q0 + 1] + bv) * ldsA_get(h_l, r0 + 1, col);
          rhp[fa][fb][qq] = pk2(rr0, rr1);
        }
      }
    __syncthreads();                         // B2: all z/r GEMM + epilogue reads of h_l done
#pragma unroll
    for (int fa = 0; fa < 2; ++fa)
#pragma unroll
      for (int fb = 0; fb < 2; ++fb) {
        const int col = wv * 64 + fb * 32 + l31;
#pragma unroll
        for (int qq = 0; qq < 8; ++qq) {
          const int q0 = 2 * qq;
          const int r0 = fa * 32 + CROW(q0, hi);
          const unsigned int w = rhp[fa][fb][qq];
          ldsA_put(h_l, r0,     col, (unsigned short)(w & 0xffffu));
          ldsA_put(h_l, r0 + 1, col, (unsigned short)(w >> 16));
        }
      }
  }
  __syncthreads();                           // B3: rh visible to all waves

  // ===== PASS h: h_hat = tanh(x Wh + rh Uh + bh); h_l now holds rh
  acc[0][0] = (f16v)(0.f); acc[0][1] = (f16v)(0.f);
  acc[1][0] = (f16v)(0.f); acc[1][1] = (f16v)(0.f);
  sweep32(acc, Bh, Bh + 16384, x_l, h_l, l31, hi);

  // ===== final epilogue: h = z*h_prev + (1-z)*h_hat (z from regs, h_prev from global)
#pragma unroll
  for (int fa = 0; fa < 2; ++fa)
#pragma unroll
    for (int fb = 0; fb < 2; ++fb) {
      const int col = wv * 64 + fb * 32 + l31;
      const float bv = bh[col];
#pragma unroll
      for (int qq = 0; qq < 8; ++qq) {
        const int q0 = 2 * qq;
        const int r0 = fa * 32 + CROW(q0, hi);
        const unsigned int zw = zp[fa][fb][qq];
#pragma unroll
        for (int j = 0; j < 2; ++j) {
          const int row = r0 + j;
          const size_t oi = (size_t)(row0 + row) * 256 + col;
          const float hh = tanh_(acc[fa][fb][q0 + j] + bv);
          const float z = bf2f((unsigned short)(j ? (zw >> 16) : (zw & 0xffffu)));
          out[oi] = z * hp[oi] + (1.0f - z) * hh;
        }
      }
    }
}

extern "C" void kernel_launch(void* const* d_in, const int* in_sizes, int n_in,
                              void* d_out, int out_size, void* d_ws, size_t ws_size,
                              hipStream_t stream) {
  const float* x  = (const float*)d_in[0];
  const float* hp = (const float*)d_in[1];
  const float* Wz = (const float*)d_in[2];
  const float* Uz = (const float*)d_in[3];
  const float* bz = (const float*)d_in[4];
  const float* Wr = (const float*)d_in[5];
  const float* Ur = (const float*)d_in[6];
  const float* br = (const float*)d_in[7];
  const float* Wh = (const float*)d_in[8];
  const float* Uh = (const float*)d_in[9];
  const float* bh = (const float*)d_in[10];

  if (ws_size < (size_t)(512 * 512 + 256 * 512) * sizeof(unsigned short)) return;  // need 768 KB

  unsigned short* wzr = (unsigned short*)d_ws;
  unsigned short* whh = wzr + 512 * 512;

  gru_prep<<<1536, 256, 0, stream>>>(Wz, Uz, Wr, Ur, Wh, Uh, wzr, whh);
  gru_main<<<1024, 256, 0, stream>>>(x, hp, wzr, whh, bz, br, bh, (float*)d_out);
}